// Round 1
// baseline (898.891 us; speedup 1.0000x reference)
//
#include <hip/hip_runtime.h>
#include <math.h>

#define S 128
#define N 512
#define P 92
#define DIN 604   // P + N
#define D 128     // all three layer dims
#define HID 256

#define BM 128
#define BN 128
#define BK 16

// ---------------- kernel: degree -> dinv ----------------
// deg[s,j] = 1 + #nonzeros in column j of conn (== row j, conn symmetric)
__global__ void k_dinv(const int* __restrict__ conn, float* __restrict__ dinv) {
    int row  = blockIdx.x * 4 + (threadIdx.x >> 6);   // 4 waves/block
    int lane = threadIdx.x & 63;
    const int* r = conn + (size_t)row * N;
    int cnt = 0;
#pragma unroll
    for (int it = 0; it < N / 64; ++it)
        cnt += (r[it * 64 + lane] != 0) ? 1 : 0;
    for (int off = 32; off > 0; off >>= 1)
        cnt += __shfl_down(cnt, off, 64);
    if (lane == 0)
        dinv[row] = rsqrtf((float)(cnt + 1));
}

// ---------------- kernel: layer-0 x@W0, dinv-scaled ----------------
// y[s,i,f] = dinv[s,i] * ( sum_{p<92} nf[s,i,p]*W0[p,f] + sum_j bf[s,i,j]*W0[92+j,f] )
__global__ __launch_bounds__(256) void k_y0(
    const float* __restrict__ nf, const float* __restrict__ bfm,
    const float* __restrict__ W0, const float* __restrict__ dinv,
    float* __restrict__ y)
{
    __shared__ __align__(16) float As[BK][BM + 4];
    __shared__ __align__(16) float Bs[BK][BN + 4];
    int s  = blockIdx.y;
    int m0 = blockIdx.x * BM;
    int tid = threadIdx.x;
    int tx = tid & 15, ty = tid >> 4;
    float acc[8][8] = {};
    const float* nfs = nf  + (size_t)s * N * P;
    const float* bfs = bfm + (size_t)s * N * N;

    for (int kt = 0; kt < DIN; kt += BK) {
        // A tile: 128 rows x 16 k, float4 chunks (512 chunks, 2/thread)
#pragma unroll
        for (int l = 0; l < 2; ++l) {
            int chunk = tid + l * 256;
            int row = chunk >> 2, c4 = chunk & 3;
            int k = kt + c4 * 4;
            int m = m0 + row;
            float4 v = make_float4(0.f, 0.f, 0.f, 0.f);
            if (k < P)        v = *(const float4*)(nfs + (size_t)m * P + k);
            else if (k < DIN) v = *(const float4*)(bfs + (size_t)m * N + (k - P));
            As[c4 * 4 + 0][row] = v.x;
            As[c4 * 4 + 1][row] = v.y;
            As[c4 * 4 + 2][row] = v.z;
            As[c4 * 4 + 3][row] = v.w;
        }
        // B tile: W0[k, f]
#pragma unroll
        for (int l = 0; l < 2; ++l) {
            int chunk = tid + l * 256;
            int krow = chunk >> 5, f4 = chunk & 31;
            int k = kt + krow;
            float4 v = make_float4(0.f, 0.f, 0.f, 0.f);
            if (k < DIN) v = *(const float4*)(W0 + (size_t)k * D + f4 * 4);
            *(float4*)&Bs[krow][f4 * 4] = v;
        }
        __syncthreads();
#pragma unroll
        for (int kk = 0; kk < BK; ++kk) {
            float a[8], b[8];
            *(float4*)&a[0] = *(const float4*)&As[kk][ty * 8];
            *(float4*)&a[4] = *(const float4*)&As[kk][ty * 8 + 4];
            *(float4*)&b[0] = *(const float4*)&Bs[kk][tx * 8];
            *(float4*)&b[4] = *(const float4*)&Bs[kk][tx * 8 + 4];
#pragma unroll
            for (int i = 0; i < 8; ++i)
#pragma unroll
                for (int j = 0; j < 8; ++j)
                    acc[i][j] += a[i] * b[j];
        }
        __syncthreads();
    }
#pragma unroll
    for (int i = 0; i < 8; ++i) {
        int m = m0 + ty * 8 + i;
        float dv = dinv[s * N + m];
        float* yr = y + ((size_t)s * N + m) * D + tx * 8;
#pragma unroll
        for (int j = 0; j < 8; j += 4) {
            float4 v = { acc[i][j] * dv, acc[i][j + 1] * dv,
                         acc[i][j + 2] * dv, acc[i][j + 3] * dv };
            *(float4*)(yr + j) = v;
        }
    }
}

// ---------------- kernel: propagate ----------------
// z[s,j,f] = bias[f] + dinv[s,j] * sum_i ((conn[s,j,i]!=0) + (i==j)) * yin[s,i,f]
// (yin already scaled by dinv[i]; conn symmetric so row j == column j)
__global__ __launch_bounds__(256) void k_prop(
    const int* __restrict__ conn, const float* __restrict__ dinv,
    const float* __restrict__ yin, const float* __restrict__ bias,
    float* __restrict__ z)
{
    __shared__ __align__(16) float As[BK][BM + 4];
    __shared__ __align__(16) float Bs[BK][BN + 4];
    int s  = blockIdx.y;
    int m0 = blockIdx.x * BM;
    int tid = threadIdx.x;
    int tx = tid & 15, ty = tid >> 4;
    float acc[8][8] = {};
    const int*   cs = conn + (size_t)s * N * N;
    const float* ys = yin  + (size_t)s * N * D;

    for (int kt = 0; kt < N; kt += BK) {
#pragma unroll
        for (int l = 0; l < 2; ++l) {
            int chunk = tid + l * 256;
            int row = chunk >> 2, c4 = chunk & 3;
            int j = m0 + row;
            int i = kt + c4 * 4;
            int4 c = *(const int4*)(cs + (size_t)j * N + i);
            As[c4 * 4 + 0][row] = (c.x != 0 ? 1.f : 0.f) + (i + 0 == j ? 1.f : 0.f);
            As[c4 * 4 + 1][row] = (c.y != 0 ? 1.f : 0.f) + (i + 1 == j ? 1.f : 0.f);
            As[c4 * 4 + 2][row] = (c.z != 0 ? 1.f : 0.f) + (i + 2 == j ? 1.f : 0.f);
            As[c4 * 4 + 3][row] = (c.w != 0 ? 1.f : 0.f) + (i + 3 == j ? 1.f : 0.f);
        }
#pragma unroll
        for (int l = 0; l < 2; ++l) {
            int chunk = tid + l * 256;
            int krow = chunk >> 5, f4 = chunk & 31;
            int k = kt + krow;
            *(float4*)&Bs[krow][f4 * 4] = *(const float4*)(ys + (size_t)k * D + f4 * 4);
        }
        __syncthreads();
#pragma unroll
        for (int kk = 0; kk < BK; ++kk) {
            float a[8], b[8];
            *(float4*)&a[0] = *(const float4*)&As[kk][ty * 8];
            *(float4*)&a[4] = *(const float4*)&As[kk][ty * 8 + 4];
            *(float4*)&b[0] = *(const float4*)&Bs[kk][tx * 8];
            *(float4*)&b[4] = *(const float4*)&Bs[kk][tx * 8 + 4];
#pragma unroll
            for (int i = 0; i < 8; ++i)
#pragma unroll
                for (int j = 0; j < 8; ++j)
                    acc[i][j] += a[i] * b[j];
        }
        __syncthreads();
    }
#pragma unroll
    for (int i = 0; i < 8; ++i) {
        int j = m0 + ty * 8 + i;
        float dv = dinv[s * N + j];
        float* zr = z + ((size_t)s * N + j) * D + tx * 8;
#pragma unroll
        for (int c = 0; c < 8; c += 4) {
            int f = tx * 8 + c;
            float4 v = { acc[i][c] * dv + bias[f],
                         acc[i][c + 1] * dv + bias[f + 1],
                         acc[i][c + 2] * dv + bias[f + 2],
                         acc[i][c + 3] * dv + bias[f + 3] };
            *(float4*)(zr + c) = v;
        }
    }
}

// ---------------- kernel: x @ W (layers 1,2), dinv-scaled ----------------
// y[m,f] = dinv[m] * sum_g zin[m,g] * W[g,f]     (m flat over S*N)
__global__ __launch_bounds__(256) void k_xw(
    const float* __restrict__ zin, const float* __restrict__ W,
    const float* __restrict__ dinv, float* __restrict__ y)
{
    __shared__ __align__(16) float As[BK][BM + 4];
    __shared__ __align__(16) float Bs[BK][BN + 4];
    int m0 = blockIdx.x * BM;
    int tid = threadIdx.x;
    int tx = tid & 15, ty = tid >> 4;
    float acc[8][8] = {};

    for (int kt = 0; kt < D; kt += BK) {
#pragma unroll
        for (int l = 0; l < 2; ++l) {
            int chunk = tid + l * 256;
            int row = chunk >> 2, c4 = chunk & 3;
            int k = kt + c4 * 4;
            float4 v = *(const float4*)(zin + (size_t)(m0 + row) * D + k);
            As[c4 * 4 + 0][row] = v.x;
            As[c4 * 4 + 1][row] = v.y;
            As[c4 * 4 + 2][row] = v.z;
            As[c4 * 4 + 3][row] = v.w;
        }
#pragma unroll
        for (int l = 0; l < 2; ++l) {
            int chunk = tid + l * 256;
            int krow = chunk >> 5, f4 = chunk & 31;
            int k = kt + krow;
            *(float4*)&Bs[krow][f4 * 4] = *(const float4*)(W + (size_t)k * D + f4 * 4);
        }
        __syncthreads();
#pragma unroll
        for (int kk = 0; kk < BK; ++kk) {
            float a[8], b[8];
            *(float4*)&a[0] = *(const float4*)&As[kk][ty * 8];
            *(float4*)&a[4] = *(const float4*)&As[kk][ty * 8 + 4];
            *(float4*)&b[0] = *(const float4*)&Bs[kk][tx * 8];
            *(float4*)&b[4] = *(const float4*)&Bs[kk][tx * 8 + 4];
#pragma unroll
            for (int i = 0; i < 8; ++i)
#pragma unroll
                for (int j = 0; j < 8; ++j)
                    acc[i][j] += a[i] * b[j];
        }
        __syncthreads();
    }
#pragma unroll
    for (int i = 0; i < 8; ++i) {
        int m = m0 + ty * 8 + i;
        float dv = dinv[m];
        float* yr = y + (size_t)m * D + tx * 8;
#pragma unroll
        for (int j = 0; j < 8; j += 4) {
            float4 v = { acc[i][j] * dv, acc[i][j + 1] * dv,
                         acc[i][j + 2] * dv, acc[i][j + 3] * dv };
            *(float4*)(yr + j) = v;
        }
    }
}

// ---------------- kernel: segment-sum pool ----------------
__global__ void k_pool(const float* __restrict__ z, float* __restrict__ pooled) {
    int s = blockIdx.x;
    int f = threadIdx.x & 127;
    int c = threadIdx.x >> 7;  // 0..3
    const float* zs = z + (size_t)s * N * D;
    float sum = 0.f;
    for (int i = c; i < N; i += 4)
        sum += zs[(size_t)i * D + f];
    __shared__ float part[4][128];
    part[c][f] = sum;
    __syncthreads();
    if (c == 0)
        pooled[s * D + f] = part[0][f] + part[1][f] + part[2][f] + part[3][f];
}

// ---------------- kernel: softplus + MLP head ----------------
__global__ __launch_bounds__(256) void k_head(
    const float* __restrict__ pooled,
    const float* __restrict__ Wh, const float* __restrict__ bh,
    const float* __restrict__ Wi, const float* __restrict__ bi,
    const float* __restrict__ We, const float* __restrict__ be,
    const float* __restrict__ Wlb, const float* __restrict__ blb,
    const float* __restrict__ Wub, const float* __restrict__ bub,
    float* __restrict__ out)
{
    int s = blockIdx.x;
    int t = threadIdx.x;
    __shared__ float sp[D];
    __shared__ float h[HID];
    if (t < D) {
        float x = pooled[s * D + t];
        sp[t] = (x > 20.f) ? x : log1pf(expf(x));
    }
    __syncthreads();
    {
        float a = bh[t];
        for (int g = 0; g < D; ++g)
            a += sp[g] * Wh[g * HID + t];
        h[t] = a;
    }
    __syncthreads();
    if (t < 100) {
        float a = bi[t];
        for (int k = 0; k < HID; ++k)
            a += h[k] * Wi[k * 100 + t];
        out[s * 100 + t] = a;
    } else if (t < 103) {
        const float* Wv = (t == 100) ? We : (t == 101) ? Wlb : Wub;
        float bv = (t == 100) ? be[0] : (t == 101) ? blb[0] : bub[0];
        float a = bv;
        for (int k = 0; k < HID; ++k)
            a += h[k] * Wv[k];
        out[S * 100 + (t - 100) * S + s] = a;
    }
}

extern "C" void kernel_launch(void* const* d_in, const int* in_sizes, int n_in,
                              void* d_out, int out_size, void* d_ws, size_t ws_size,
                              hipStream_t stream) {
    const float* nf   = (const float*)d_in[0];
    const float* bfm  = (const float*)d_in[1];
    const int*   conn = (const int*)d_in[2];
    // d_in[3] batchAssign: implicit (repeat of arange), unused
    const float* W0 = (const float*)d_in[4];
    const float* b0 = (const float*)d_in[5];
    const float* W1 = (const float*)d_in[6];
    const float* b1 = (const float*)d_in[7];
    const float* W2 = (const float*)d_in[8];
    const float* b2 = (const float*)d_in[9];
    const float* Wh = (const float*)d_in[10];
    const float* bh = (const float*)d_in[11];
    const float* Wi = (const float*)d_in[12];
    const float* bi = (const float*)d_in[13];
    const float* We = (const float*)d_in[14];
    const float* be = (const float*)d_in[15];
    const float* Wlb = (const float*)d_in[16];
    const float* blb = (const float*)d_in[17];
    const float* Wub = (const float*)d_in[18];
    const float* bub = (const float*)d_in[19];
    float* out = (float*)d_out;

    char* ws = (char*)d_ws;
    float* dinv   = (float*)ws;                                    // 256 KB
    float* ybuf   = (float*)(ws + (1u << 18));                     // 32 MB
    float* zbuf   = (float*)(ws + (1u << 18) + (1u << 25));        // 32 MB
    float* pooled = (float*)(ws + (1u << 18) + (1u << 26));        // 64 KB

    k_dinv<<<S * N / 4, 256, 0, stream>>>(conn, dinv);
    k_y0<<<dim3(N / BM, S), 256, 0, stream>>>(nf, bfm, W0, dinv, ybuf);
    k_prop<<<dim3(N / BM, S), 256, 0, stream>>>(conn, dinv, ybuf, b0, zbuf);
    k_xw<<<S * N / BM, 256, 0, stream>>>(zbuf, W1, dinv, ybuf);
    k_prop<<<dim3(N / BM, S), 256, 0, stream>>>(conn, dinv, ybuf, b1, zbuf);
    k_xw<<<S * N / BM, 256, 0, stream>>>(zbuf, W2, dinv, ybuf);
    k_prop<<<dim3(N / BM, S), 256, 0, stream>>>(conn, dinv, ybuf, b2, zbuf);
    k_pool<<<S, 512, 0, stream>>>(zbuf, pooled);
    k_head<<<S, 256, 0, stream>>>(pooled, Wh, bh, Wi, bi, We, be, Wlb, blb, Wub, bub, out);
}

// Round 2
// 764.303 us; speedup vs baseline: 1.1761x; 1.1761x over previous
//
#include <hip/hip_runtime.h>
#include <math.h>

#define S 128
#define N 512
#define P 92
#define DIN 604   // P + N
#define D 128     // all three layer dims
#define HID 256

#define BM 128
#define BN 128
#define BK 16

// ---------------- kernel: pre-pass over conn ----------------
// Reads conn ONCE: builds 512-bit adjacency row masks (u64 x8 per row),
// dinv[row] = rsqrt(deg+1), and zeroes the pooled accumulator.
__global__ void k_pre(const int* __restrict__ conn,
                      unsigned long long* __restrict__ mask,
                      float* __restrict__ dinv,
                      float* __restrict__ pooled) {
    // zero pooled (S*D = 16384 floats) using first 64 blocks
    int zidx = blockIdx.x * 256 + (int)threadIdx.x;
    if (zidx < S * D) pooled[zidx] = 0.f;

    int row  = blockIdx.x * 4 + (threadIdx.x >> 6);   // flat over S*N
    int lane = threadIdx.x & 63;
    const int* r = conn + (size_t)row * N;
    int deg = 0;
#pragma unroll
    for (int w = 0; w < 8; ++w) {
        int c = r[w * 64 + lane];
        unsigned long long b = __ballot(c != 0);
        deg += __popcll(b);
        if (lane == 0) mask[(size_t)row * 8 + w] = b;
    }
    if (lane == 0) dinv[row] = rsqrtf((float)(deg + 1));
}

// ---------------- kernel: layer-0 x@W0, dinv-scaled ----------------
// y[s,i,f] = dinv[s,i] * ( nf[s,i,:]@W0[:92,f] + bf[s,i,:]@W0[92:,f] )
__global__ __launch_bounds__(256) void k_y0(
    const float* __restrict__ nf, const float* __restrict__ bfm,
    const float* __restrict__ W0, const float* __restrict__ dinv,
    float* __restrict__ y)
{
    __shared__ __align__(16) float As[BK][BM + 4];
    __shared__ __align__(16) float Bs[BK][BN + 4];
    int s  = blockIdx.y;
    int m0 = blockIdx.x * BM;
    int tid = threadIdx.x;
    int tx = tid & 15, ty = tid >> 4;
    float acc[8][8] = {};
    const float* nfs = nf  + (size_t)s * N * P;
    const float* bfs = bfm + (size_t)s * N * N;

    for (int kt = 0; kt < DIN; kt += BK) {
#pragma unroll
        for (int l = 0; l < 2; ++l) {
            int chunk = tid + l * 256;
            int row = chunk >> 2, c4 = chunk & 3;
            int k = kt + c4 * 4;
            int m = m0 + row;
            float4 v = make_float4(0.f, 0.f, 0.f, 0.f);
            if (k < P)        v = *(const float4*)(nfs + (size_t)m * P + k);
            else if (k < DIN) v = *(const float4*)(bfs + (size_t)m * N + (k - P));
            As[c4 * 4 + 0][row] = v.x;
            As[c4 * 4 + 1][row] = v.y;
            As[c4 * 4 + 2][row] = v.z;
            As[c4 * 4 + 3][row] = v.w;
        }
#pragma unroll
        for (int l = 0; l < 2; ++l) {
            int chunk = tid + l * 256;
            int krow = chunk >> 5, f4 = chunk & 31;
            int k = kt + krow;
            float4 v = make_float4(0.f, 0.f, 0.f, 0.f);
            if (k < DIN) v = *(const float4*)(W0 + (size_t)k * D + f4 * 4);
            *(float4*)&Bs[krow][f4 * 4] = v;
        }
        __syncthreads();
#pragma unroll
        for (int kk = 0; kk < BK; ++kk) {
            float a[8], b[8];
            *(float4*)&a[0] = *(const float4*)&As[kk][ty * 8];
            *(float4*)&a[4] = *(const float4*)&As[kk][ty * 8 + 4];
            // bank-conflict fix: two 4-float groups (stride 4 -> 2-way, free)
            *(float4*)&b[0] = *(const float4*)&Bs[kk][tx * 4];
            *(float4*)&b[4] = *(const float4*)&Bs[kk][64 + tx * 4];
#pragma unroll
            for (int i = 0; i < 8; ++i)
#pragma unroll
                for (int j = 0; j < 8; ++j)
                    acc[i][j] += a[i] * b[j];
        }
        __syncthreads();
    }
#pragma unroll
    for (int i = 0; i < 8; ++i) {
        int m = m0 + ty * 8 + i;
        float dv = dinv[s * N + m];
        float* yr = y + ((size_t)s * N + m) * D;
        float4 v0 = { acc[i][0] * dv, acc[i][1] * dv, acc[i][2] * dv, acc[i][3] * dv };
        float4 v1 = { acc[i][4] * dv, acc[i][5] * dv, acc[i][6] * dv, acc[i][7] * dv };
        *(float4*)(yr + tx * 4) = v0;
        *(float4*)(yr + 64 + tx * 4) = v1;
    }
}

// ---------------- kernel: sparse propagate ----------------
// z[s,j,f] = bias[f] + dinv[s,j] * ( y[s,j,f] + sum_{i in mask row j} y[s,i,f] )
// (y pre-scaled by dinv_i; self-loop handled by init; conn[j][j]!=0 -> coeff 2 via bit j)
// If pooled != nullptr: instead of writing z, LDS-reduce the 8 targets and atomicAdd.
__global__ __launch_bounds__(256) void k_prop_sparse(
    const unsigned long long* __restrict__ mask, const float* __restrict__ dinv,
    const float* __restrict__ yin, const float* __restrict__ bias,
    float* __restrict__ z, float* __restrict__ pooled)
{
    int s  = blockIdx.y;
    int g  = threadIdx.x >> 5;           // 0..7 target groups
    int j  = blockIdx.x * 8 + g;
    int f4 = threadIdx.x & 31;           // features [f4*4, f4*4+4)
    const float* ys = yin + (size_t)s * N * D;
    const unsigned long long* mrow = mask + ((size_t)s * N + j) * 8;

    float4 acc = *(const float4*)(ys + (size_t)j * D + f4 * 4);  // +I self loop

    int w = 0;
    unsigned long long bits = mrow[0];
    // advance to next set bit and issue its load
    auto next_load = [&](float4& dst) -> bool {
        while (bits == 0) {
            if (++w >= 8) return false;
            bits = mrow[w];
        }
        int i = (w << 6) + __builtin_ctzll(bits);
        bits &= bits - 1;
        dst = *(const float4*)(ys + (size_t)i * D + f4 * 4);
        return true;
    };

    float4 cur, nxt;
    bool h = next_load(cur);
    while (h) {
        bool h2 = next_load(nxt);       // load in flight while adding cur
        acc.x += cur.x; acc.y += cur.y; acc.z += cur.z; acc.w += cur.w;
        cur = nxt; h = h2;
    }

    float dv = dinv[s * N + j];
    int f = f4 * 4;
    float4 r = { acc.x * dv + bias[f],     acc.y * dv + bias[f + 1],
                 acc.z * dv + bias[f + 2], acc.w * dv + bias[f + 3] };

    if (pooled == nullptr) {
        *(float4*)(z + ((size_t)s * N + j) * D + f) = r;
    } else {
        __shared__ float red[8][D];
        *(float4*)&red[g][f] = r;
        __syncthreads();
        if (threadIdx.x < D) {
            float t = 0.f;
#pragma unroll
            for (int q = 0; q < 8; ++q) t += red[q][threadIdx.x];
            atomicAdd(pooled + s * D + threadIdx.x, t);
        }
    }
}

// ---------------- kernel: x @ W (layers 1,2), dinv-scaled ----------------
__global__ __launch_bounds__(256) void k_xw(
    const float* __restrict__ zin, const float* __restrict__ W,
    const float* __restrict__ dinv, float* __restrict__ y)
{
    __shared__ __align__(16) float As[BK][BM + 4];
    __shared__ __align__(16) float Bs[BK][BN + 4];
    int m0 = blockIdx.x * BM;
    int tid = threadIdx.x;
    int tx = tid & 15, ty = tid >> 4;
    float acc[8][8] = {};

    for (int kt = 0; kt < D; kt += BK) {
#pragma unroll
        for (int l = 0; l < 2; ++l) {
            int chunk = tid + l * 256;
            int row = chunk >> 2, c4 = chunk & 3;
            int k = kt + c4 * 4;
            float4 v = *(const float4*)(zin + (size_t)(m0 + row) * D + k);
            As[c4 * 4 + 0][row] = v.x;
            As[c4 * 4 + 1][row] = v.y;
            As[c4 * 4 + 2][row] = v.z;
            As[c4 * 4 + 3][row] = v.w;
        }
#pragma unroll
        for (int l = 0; l < 2; ++l) {
            int chunk = tid + l * 256;
            int krow = chunk >> 5, f4 = chunk & 31;
            int k = kt + krow;
            *(float4*)&Bs[krow][f4 * 4] = *(const float4*)(W + (size_t)k * D + f4 * 4);
        }
        __syncthreads();
#pragma unroll
        for (int kk = 0; kk < BK; ++kk) {
            float a[8], b[8];
            *(float4*)&a[0] = *(const float4*)&As[kk][ty * 8];
            *(float4*)&a[4] = *(const float4*)&As[kk][ty * 8 + 4];
            *(float4*)&b[0] = *(const float4*)&Bs[kk][tx * 4];
            *(float4*)&b[4] = *(const float4*)&Bs[kk][64 + tx * 4];
#pragma unroll
            for (int i = 0; i < 8; ++i)
#pragma unroll
                for (int j = 0; j < 8; ++j)
                    acc[i][j] += a[i] * b[j];
        }
        __syncthreads();
    }
#pragma unroll
    for (int i = 0; i < 8; ++i) {
        int m = m0 + ty * 8 + i;
        float dv = dinv[m];
        float* yr = y + (size_t)m * D;
        float4 v0 = { acc[i][0] * dv, acc[i][1] * dv, acc[i][2] * dv, acc[i][3] * dv };
        float4 v1 = { acc[i][4] * dv, acc[i][5] * dv, acc[i][6] * dv, acc[i][7] * dv };
        *(float4*)(yr + tx * 4) = v0;
        *(float4*)(yr + 64 + tx * 4) = v1;
    }
}

// ---------------- kernel: softplus + MLP head ----------------
__global__ __launch_bounds__(256) void k_head(
    const float* __restrict__ pooled,
    const float* __restrict__ Wh, const float* __restrict__ bh,
    const float* __restrict__ Wi, const float* __restrict__ bi,
    const float* __restrict__ We, const float* __restrict__ be,
    const float* __restrict__ Wlb, const float* __restrict__ blb,
    const float* __restrict__ Wub, const float* __restrict__ bub,
    float* __restrict__ out)
{
    int s = blockIdx.x;
    int t = threadIdx.x;
    __shared__ float sp[D];
    __shared__ float h[HID];
    if (t < D) {
        float x = pooled[s * D + t];
        sp[t] = (x > 20.f) ? x : log1pf(expf(x));
    }
    __syncthreads();
    {
        float a = bh[t];
        for (int g = 0; g < D; ++g)
            a += sp[g] * Wh[g * HID + t];
        h[t] = a;
    }
    __syncthreads();
    if (t < 100) {
        float a = bi[t];
        for (int k = 0; k < HID; ++k)
            a += h[k] * Wi[k * 100 + t];
        out[s * 100 + t] = a;
    } else if (t < 103) {
        const float* Wv = (t == 100) ? We : (t == 101) ? Wlb : Wub;
        float bv = (t == 100) ? be[0] : (t == 101) ? blb[0] : bub[0];
        float a = bv;
        for (int k = 0; k < HID; ++k)
            a += h[k] * Wv[k];
        out[S * 100 + (t - 100) * S + s] = a;
    }
}

extern "C" void kernel_launch(void* const* d_in, const int* in_sizes, int n_in,
                              void* d_out, int out_size, void* d_ws, size_t ws_size,
                              hipStream_t stream) {
    const float* nf   = (const float*)d_in[0];
    const float* bfm  = (const float*)d_in[1];
    const int*   conn = (const int*)d_in[2];
    const float* W0 = (const float*)d_in[4];
    const float* b0 = (const float*)d_in[5];
    const float* W1 = (const float*)d_in[6];
    const float* b1 = (const float*)d_in[7];
    const float* W2 = (const float*)d_in[8];
    const float* b2 = (const float*)d_in[9];
    const float* Wh = (const float*)d_in[10];
    const float* bh = (const float*)d_in[11];
    const float* Wi = (const float*)d_in[12];
    const float* bi = (const float*)d_in[13];
    const float* We = (const float*)d_in[14];
    const float* be = (const float*)d_in[15];
    const float* Wlb = (const float*)d_in[16];
    const float* blb = (const float*)d_in[17];
    const float* Wub = (const float*)d_in[18];
    const float* bub = (const float*)d_in[19];
    float* out = (float*)d_out;

    char* ws = (char*)d_ws;
    float* ybuf = (float*)ws;                                   // 32 MB (2^25)
    float* zbuf = (float*)(ws + (1u << 25));                    // 32 MB
    float* dinv = (float*)(ws + (1u << 26));                    // 256 KB
    float* pooled = (float*)(ws + (1u << 26) + (1u << 18));     // 64 KB
    unsigned long long* mask =
        (unsigned long long*)(ws + (1u << 26) + (1u << 18) + (1u << 16)); // 4 MB

    k_pre<<<S * N / 4, 256, 0, stream>>>(conn, mask, dinv, pooled);
    k_y0<<<dim3(N / BM, S), 256, 0, stream>>>(nf, bfm, W0, dinv, ybuf);
    k_prop_sparse<<<dim3(N / 8, S), 256, 0, stream>>>(mask, dinv, ybuf, b0, zbuf, nullptr);
    k_xw<<<S * N / BM, 256, 0, stream>>>(zbuf, W1, dinv, ybuf);
    k_prop_sparse<<<dim3(N / 8, S), 256, 0, stream>>>(mask, dinv, ybuf, b1, zbuf, nullptr);
    k_xw<<<S * N / BM, 256, 0, stream>>>(zbuf, W2, dinv, ybuf);
    k_prop_sparse<<<dim3(N / 8, S), 256, 0, stream>>>(mask, dinv, ybuf, b2, zbuf, pooled);
    k_head<<<S, 256, 0, stream>>>(pooled, Wh, bh, Wi, bi, We, be, Wlb, blb, Wub, bub, out);
}

// Round 3
// 679.337 us; speedup vs baseline: 1.3232x; 1.1251x over previous
//
#include <hip/hip_runtime.h>
#include <math.h>

#define S 128
#define N 512
#define P 92
#define DIN 604   // P + N
#define D 128     // all three layer dims
#define HID 256
#define MAXDEG 64

#define BK 16

// ---------------- kernel: pre-pass over conn ----------------
// Reads conn ONCE: builds padded CSR (u16 idx[row][64] + deg), dinv, zeroes pooled.
// Parallel compaction: ballot + popcount-below-lane gives each set bit its slot.
__global__ void k_pre(const int* __restrict__ conn,
                      unsigned short* __restrict__ idx,
                      int* __restrict__ degs,
                      float* __restrict__ dinv,
                      float* __restrict__ pooled) {
    int zidx = blockIdx.x * 256 + (int)threadIdx.x;
    if (zidx < S * D) pooled[zidx] = 0.f;

    int row  = blockIdx.x * 4 + (threadIdx.x >> 6);   // flat over S*N
    int lane = threadIdx.x & 63;
    const int* r = conn + (size_t)row * N;
    unsigned short* irow = idx + (size_t)row * MAXDEG;
    int deg = 0;
#pragma unroll
    for (int w = 0; w < 8; ++w) {
        int c = r[w * 64 + lane];
        unsigned long long bits = __ballot(c != 0);
        int below = __popcll(bits & ((1ull << lane) - 1ull));
        if (c != 0) {
            int pos = deg + below;
            if (pos < MAXDEG) irow[pos] = (unsigned short)(w * 64 + lane);
        }
        deg += __popcll(bits);
    }
    if (lane == 0) {
        degs[row] = deg < MAXDEG ? deg : MAXDEG;
        dinv[row] = rsqrtf((float)(deg + 1));
    }
}

// ---------------- kernel: layer-0 x@W0, dinv-scaled (BM=64) ----------------
__global__ __launch_bounds__(256) void k_y0(
    const float* __restrict__ nf, const float* __restrict__ bfm,
    const float* __restrict__ W0, const float* __restrict__ dinv,
    float* __restrict__ y)
{
    __shared__ __align__(16) float As[BK][64 + 4];
    __shared__ __align__(16) float Bs[BK][128 + 4];
    int s  = blockIdx.y;
    int m0 = blockIdx.x * 64;
    int tid = threadIdx.x;
    int tx = tid & 15, ty = tid >> 4;
    float acc[4][8] = {};
    const float* nfs = nf  + (size_t)s * N * P;
    const float* bfs = bfm + (size_t)s * N * N;

    for (int kt = 0; kt < DIN; kt += BK) {
        {   // A tile: 64 rows x 16 k = 256 float4, 1/thread
            int row = tid >> 2, c4 = tid & 3;
            int k = kt + c4 * 4;
            int m = m0 + row;
            float4 v = make_float4(0.f, 0.f, 0.f, 0.f);
            if (k < P)        v = *(const float4*)(nfs + (size_t)m * P + k);
            else if (k < DIN) v = *(const float4*)(bfs + (size_t)m * N + (k - P));
            As[c4 * 4 + 0][row] = v.x;
            As[c4 * 4 + 1][row] = v.y;
            As[c4 * 4 + 2][row] = v.z;
            As[c4 * 4 + 3][row] = v.w;
        }
#pragma unroll
        for (int l = 0; l < 2; ++l) {   // B tile: 16 x 128 = 512 float4, 2/thread
            int chunk = tid + l * 256;
            int krow = chunk >> 5, f4 = chunk & 31;
            int k = kt + krow;
            float4 v = make_float4(0.f, 0.f, 0.f, 0.f);
            if (k < DIN) v = *(const float4*)(W0 + (size_t)k * D + f4 * 4);
            *(float4*)&Bs[krow][f4 * 4] = v;
        }
        __syncthreads();
#pragma unroll
        for (int kk = 0; kk < BK; ++kk) {
            float a[4], b[8];
            *(float4*)&a[0] = *(const float4*)&As[kk][ty * 4];
            *(float4*)&b[0] = *(const float4*)&Bs[kk][tx * 4];
            *(float4*)&b[4] = *(const float4*)&Bs[kk][64 + tx * 4];
#pragma unroll
            for (int i = 0; i < 4; ++i)
#pragma unroll
                for (int j = 0; j < 8; ++j)
                    acc[i][j] += a[i] * b[j];
        }
        __syncthreads();
    }
#pragma unroll
    for (int i = 0; i < 4; ++i) {
        int m = m0 + ty * 4 + i;
        float dv = dinv[s * N + m];
        float* yr = y + ((size_t)s * N + m) * D;
        float4 v0 = { acc[i][0] * dv, acc[i][1] * dv, acc[i][2] * dv, acc[i][3] * dv };
        float4 v1 = { acc[i][4] * dv, acc[i][5] * dv, acc[i][6] * dv, acc[i][7] * dv };
        *(float4*)(yr + tx * 4) = v0;
        *(float4*)(yr + 64 + tx * 4) = v1;
    }
}

// ---------------- kernel: sparse propagate via CSR, 8-deep pipelined ----------------
// z[s,j,f] = bias[f] + dinv[s,j] * ( y[s,j,f] + sum_{i in csr row j} y[s,i,f] )
__global__ __launch_bounds__(256) void k_prop_csr(
    const unsigned short* __restrict__ idx, const int* __restrict__ degs,
    const float* __restrict__ dinv,
    const float* __restrict__ yin, const float* __restrict__ bias,
    float* __restrict__ z, float* __restrict__ pooled)
{
    __shared__ unsigned short sidx[8][MAXDEG];  // 1 KB
    __shared__ int sdeg[8];
    int s  = blockIdx.y;
    int g  = threadIdx.x >> 5;           // 0..7 target groups
    int j  = blockIdx.x * 8 + g;
    int f4 = threadIdx.x & 31;           // feature quad
    const float* ys = yin + (size_t)s * N * D;

    // stage CSR rows for the 8 targets: 8*64 u16 = 256 u32, 1/thread
    {
        int tg = threadIdx.x >> 5, pair = threadIdx.x & 31;
        const unsigned int* src = (const unsigned int*)(idx + ((size_t)(s * N + blockIdx.x * 8 + tg)) * MAXDEG);
        ((unsigned int*)&sidx[tg][0])[pair] = src[pair];
        if (threadIdx.x < 8) sdeg[threadIdx.x] = degs[s * N + blockIdx.x * 8 + threadIdx.x];
    }
    __syncthreads();

    float4 acc = *(const float4*)(ys + (size_t)j * D + f4 * 4);  // +I self loop
    int d = sdeg[g];
    int b = 0;
    for (; b + 8 <= d; b += 8) {
        float4 v[8];
#pragma unroll
        for (int q = 0; q < 8; ++q) {
            int i = sidx[g][b + q];
            v[q] = *(const float4*)(ys + (size_t)i * D + f4 * 4);
        }
#pragma unroll
        for (int q = 0; q < 8; ++q) {
            acc.x += v[q].x; acc.y += v[q].y; acc.z += v[q].z; acc.w += v[q].w;
        }
    }
    for (; b < d; ++b) {
        int i = sidx[g][b];
        float4 v = *(const float4*)(ys + (size_t)i * D + f4 * 4);
        acc.x += v.x; acc.y += v.y; acc.z += v.z; acc.w += v.w;
    }

    float dv = dinv[s * N + j];
    int f = f4 * 4;
    float4 r = { acc.x * dv + bias[f],     acc.y * dv + bias[f + 1],
                 acc.z * dv + bias[f + 2], acc.w * dv + bias[f + 3] };

    if (pooled == nullptr) {
        *(float4*)(z + ((size_t)s * N + j) * D + f) = r;
    } else {
        __shared__ float red[8][D];
        *(float4*)&red[g][f] = r;
        __syncthreads();
        if (threadIdx.x < D) {
            float t = 0.f;
#pragma unroll
            for (int q = 0; q < 8; ++q) t += red[q][threadIdx.x];
            atomicAdd(pooled + s * D + threadIdx.x, t);
        }
    }
}

// ---------------- kernel: x @ W (layers 1,2), dinv-scaled (BM=64) ----------------
__global__ __launch_bounds__(256) void k_xw(
    const float* __restrict__ zin, const float* __restrict__ W,
    const float* __restrict__ dinv, float* __restrict__ y)
{
    __shared__ __align__(16) float As[BK][64 + 4];
    __shared__ __align__(16) float Bs[BK][128 + 4];
    int m0 = blockIdx.x * 64;
    int tid = threadIdx.x;
    int tx = tid & 15, ty = tid >> 4;
    float acc[4][8] = {};

    for (int kt = 0; kt < D; kt += BK) {
        {
            int row = tid >> 2, c4 = tid & 3;
            int k = kt + c4 * 4;
            float4 v = *(const float4*)(zin + (size_t)(m0 + row) * D + k);
            As[c4 * 4 + 0][row] = v.x;
            As[c4 * 4 + 1][row] = v.y;
            As[c4 * 4 + 2][row] = v.z;
            As[c4 * 4 + 3][row] = v.w;
        }
#pragma unroll
        for (int l = 0; l < 2; ++l) {
            int chunk = tid + l * 256;
            int krow = chunk >> 5, f4 = chunk & 31;
            int k = kt + krow;
            *(float4*)&Bs[krow][f4 * 4] = *(const float4*)(W + (size_t)k * D + f4 * 4);
        }
        __syncthreads();
#pragma unroll
        for (int kk = 0; kk < BK; ++kk) {
            float a[4], b[8];
            *(float4*)&a[0] = *(const float4*)&As[kk][ty * 4];
            *(float4*)&b[0] = *(const float4*)&Bs[kk][tx * 4];
            *(float4*)&b[4] = *(const float4*)&Bs[kk][64 + tx * 4];
#pragma unroll
            for (int i = 0; i < 4; ++i)
#pragma unroll
                for (int j = 0; j < 8; ++j)
                    acc[i][j] += a[i] * b[j];
        }
        __syncthreads();
    }
#pragma unroll
    for (int i = 0; i < 4; ++i) {
        int m = m0 + ty * 4 + i;
        float dv = dinv[m];
        float* yr = y + (size_t)m * D;
        float4 v0 = { acc[i][0] * dv, acc[i][1] * dv, acc[i][2] * dv, acc[i][3] * dv };
        float4 v1 = { acc[i][4] * dv, acc[i][5] * dv, acc[i][6] * dv, acc[i][7] * dv };
        *(float4*)(yr + tx * 4) = v0;
        *(float4*)(yr + 64 + tx * 4) = v1;
    }
}

// ---------------- kernel: softplus + MLP head ----------------
__global__ __launch_bounds__(256) void k_head(
    const float* __restrict__ pooled,
    const float* __restrict__ Wh, const float* __restrict__ bh,
    const float* __restrict__ Wi, const float* __restrict__ bi,
    const float* __restrict__ We, const float* __restrict__ be,
    const float* __restrict__ Wlb, const float* __restrict__ blb,
    const float* __restrict__ Wub, const float* __restrict__ bub,
    float* __restrict__ out)
{
    int s = blockIdx.x;
    int t = threadIdx.x;
    __shared__ float sp[D];
    __shared__ float h[HID];
    if (t < D) {
        float x = pooled[s * D + t];
        sp[t] = (x > 20.f) ? x : log1pf(expf(x));
    }
    __syncthreads();
    {
        float a = bh[t];
        for (int g = 0; g < D; ++g)
            a += sp[g] * Wh[g * HID + t];
        h[t] = a;
    }
    __syncthreads();
    if (t < 100) {
        float a = bi[t];
        for (int k = 0; k < HID; ++k)
            a += h[k] * Wi[k * 100 + t];
        out[s * 100 + t] = a;
    } else if (t < 103) {
        const float* Wv = (t == 100) ? We : (t == 101) ? Wlb : Wub;
        float bv = (t == 100) ? be[0] : (t == 101) ? blb[0] : bub[0];
        float a = bv;
        for (int k = 0; k < HID; ++k)
            a += h[k] * Wv[k];
        out[S * 100 + (t - 100) * S + s] = a;
    }
}

extern "C" void kernel_launch(void* const* d_in, const int* in_sizes, int n_in,
                              void* d_out, int out_size, void* d_ws, size_t ws_size,
                              hipStream_t stream) {
    const float* nf   = (const float*)d_in[0];
    const float* bfm  = (const float*)d_in[1];
    const int*   conn = (const int*)d_in[2];
    const float* W0 = (const float*)d_in[4];
    const float* b0 = (const float*)d_in[5];
    const float* W1 = (const float*)d_in[6];
    const float* b1 = (const float*)d_in[7];
    const float* W2 = (const float*)d_in[8];
    const float* b2 = (const float*)d_in[9];
    const float* Wh = (const float*)d_in[10];
    const float* bh = (const float*)d_in[11];
    const float* Wi = (const float*)d_in[12];
    const float* bi = (const float*)d_in[13];
    const float* We = (const float*)d_in[14];
    const float* be = (const float*)d_in[15];
    const float* Wlb = (const float*)d_in[16];
    const float* blb = (const float*)d_in[17];
    const float* Wub = (const float*)d_in[18];
    const float* bub = (const float*)d_in[19];
    float* out = (float*)d_out;

    char* ws = (char*)d_ws;
    float* ybuf = (float*)ws;                                   // 32 MB
    float* zbuf = (float*)(ws + (1u << 25));                    // 32 MB
    float* dinv = (float*)(ws + (1u << 26));                    // 256 KB
    int*   degs = (int*)(ws + (1u << 26) + (1u << 18));         // 256 KB
    float* pooled = (float*)(ws + (1u << 26) + (1u << 19));     // 64 KB
    unsigned short* idx =
        (unsigned short*)(ws + (1u << 26) + (1u << 19) + (1u << 16)); // 8 MB

    k_pre<<<S * N / 4, 256, 0, stream>>>(conn, idx, degs, dinv, pooled);
    k_y0<<<dim3(N / 64, S), 256, 0, stream>>>(nf, bfm, W0, dinv, ybuf);
    k_prop_csr<<<dim3(N / 8, S), 256, 0, stream>>>(idx, degs, dinv, ybuf, b0, zbuf, nullptr);
    k_xw<<<S * N / 64, 256, 0, stream>>>(zbuf, W1, dinv, ybuf);
    k_prop_csr<<<dim3(N / 8, S), 256, 0, stream>>>(idx, degs, dinv, ybuf, b1, zbuf, nullptr);
    k_xw<<<S * N / 64, 256, 0, stream>>>(zbuf, W2, dinv, ybuf);
    k_prop_csr<<<dim3(N / 8, S), 256, 0, stream>>>(idx, degs, dinv, ybuf, b2, zbuf, pooled);
    k_head<<<S, 256, 0, stream>>>(pooled, Wh, bh, Wi, bi, We, be, Wlb, blb, Wub, bub, out);
}

// Round 4
// 615.875 us; speedup vs baseline: 1.4595x; 1.1030x over previous
//
#include <hip/hip_runtime.h>
#include <hip/hip_bf16.h>
#include <math.h>

#define S 128
#define N 512
#define P 92
#define DIN 604   // P + N
#define KPAD0 608 // DIN padded to 32
#define D 128
#define HID 256
#define MAXDEG 64

typedef __attribute__((ext_vector_type(8))) short frag8;     // 8 bf16
typedef __attribute__((ext_vector_type(4))) float floatx4;   // 4 fp32 acc

__device__ inline void split1(float x, unsigned short& h, unsigned short& l) {
    __hip_bfloat16 hb = __float2bfloat16(x);
    float hf = __bfloat162float(hb);
    __hip_bfloat16 lb = __float2bfloat16(x - hf);
    h = *(unsigned short*)&hb;
    l = *(unsigned short*)&lb;
}

// ---------------- pre-pass over conn: CSR + dinv + zero pooled ----------------
__global__ void k_pre(const int* __restrict__ conn,
                      unsigned short* __restrict__ idx,
                      int* __restrict__ degs,
                      float* __restrict__ dinv,
                      float* __restrict__ pooled) {
    int zidx = blockIdx.x * 256 + (int)threadIdx.x;
    if (zidx < S * D) pooled[zidx] = 0.f;

    int row  = blockIdx.x * 4 + (threadIdx.x >> 6);
    int lane = threadIdx.x & 63;
    const int* r = conn + (size_t)row * N;
    unsigned short* irow = idx + (size_t)row * MAXDEG;
    int deg = 0;
#pragma unroll
    for (int w = 0; w < 8; ++w) {
        int c = r[w * 64 + lane];
        unsigned long long bits = __ballot(c != 0);
        int below = __popcll(bits & ((1ull << lane) - 1ull));
        if (c != 0) {
            int pos = deg + below;
            if (pos < MAXDEG) irow[pos] = (unsigned short)(w * 64 + lane);
        }
        deg += __popcll(bits);
    }
    if (lane == 0) {
        degs[row] = deg < MAXDEG ? deg : MAXDEG;
        dinv[row] = rsqrtf((float)(deg + 1));
    }
}

// ---------------- weight transform: W[K][128] -> Wt_hi/lo[n][Kpad] bf16 ----------------
__global__ void k_wt(const float* __restrict__ W, int K, int Kpad,
                     unsigned short* __restrict__ th, unsigned short* __restrict__ tl) {
    int i = blockIdx.x * 256 + threadIdx.x;           // over Kpad*128
    if (i >= Kpad * 128) return;
    int k = i >> 7, n = i & 127;
    float v = (k < K) ? W[(size_t)k * 128 + n] : 0.f;
    unsigned short h, l;
    split1(v, h, l);
    th[(size_t)n * Kpad + k] = h;
    tl[(size_t)n * Kpad + k] = l;
}

// ---------------- layer-0: y = dinv .* ([nf|bf] @ W0), split-bf16 MFMA ----------------
__global__ __launch_bounds__(128) void k_y0_mfma(
    const float* __restrict__ nf, const float* __restrict__ bfm,
    const unsigned short* __restrict__ w0th, const unsigned short* __restrict__ w0tl,
    const float* __restrict__ dinv, float* __restrict__ y)
{
    __shared__ __align__(16) unsigned short As_hi[64][32], As_lo[64][32];
    __shared__ __align__(16) unsigned short Bs_hi[128][32], Bs_lo[128][32];
    int s  = blockIdx.y;
    int m0 = blockIdx.x * 64;
    int tid = threadIdx.x;
    int lane = tid & 63, w = tid >> 6;
    int lr = lane & 15, q = lane >> 4;
    const float* nfs = nf  + (size_t)s * N * P;
    const float* bfs = bfm + (size_t)s * N * N;

    floatx4 acc[2][8];
#pragma unroll
    for (int r = 0; r < 2; ++r)
#pragma unroll
        for (int c = 0; c < 8; ++c)
            acc[r][c] = (floatx4){0.f, 0.f, 0.f, 0.f};

    for (int kc = 0; kc < KPAD0 / 32; ++kc) {
        int k0 = kc * 32;
        // A: 64 rows x 32 k fp32 -> split bf16. 512 quads, 4/thread.
#pragma unroll
        for (int l = 0; l < 4; ++l) {
            int i2 = tid + l * 128;
            int row = i2 >> 3, q4 = i2 & 7;
            int k = k0 + q4 * 4;
            int m = m0 + row;
            float4 v = make_float4(0.f, 0.f, 0.f, 0.f);
            if (k < P)        v = *(const float4*)(nfs + (size_t)m * P + k);
            else if (k < DIN) v = *(const float4*)(bfs + (size_t)m * N + (k - P));
            ushort4 h, lo;
            split1(v.x, h.x, lo.x); split1(v.y, h.y, lo.y);
            split1(v.z, h.z, lo.z); split1(v.w, h.w, lo.w);
            *(ushort4*)&As_hi[row][q4 * 4] = h;
            *(ushort4*)&As_lo[row][q4 * 4] = lo;
        }
        // B: 128 n x 32 k bf16 copy (16B chunks), 512 chunks, 4/thread per buf
#pragma unroll
        for (int l = 0; l < 4; ++l) {
            int i2 = tid + l * 128;
            int n = i2 >> 2, q8 = i2 & 3;
            *(uint4*)&Bs_hi[n][q8 * 8] = *(const uint4*)(w0th + (size_t)n * KPAD0 + k0 + q8 * 8);
            *(uint4*)&Bs_lo[n][q8 * 8] = *(const uint4*)(w0tl + (size_t)n * KPAD0 + k0 + q8 * 8);
        }
        __syncthreads();
        frag8 a_h[2], a_l[2];
        a_h[0] = *(const frag8*)&As_hi[32 * w + lr][q * 8];
        a_h[1] = *(const frag8*)&As_hi[32 * w + 16 + lr][q * 8];
        a_l[0] = *(const frag8*)&As_lo[32 * w + lr][q * 8];
        a_l[1] = *(const frag8*)&As_lo[32 * w + 16 + lr][q * 8];
#pragma unroll
        for (int c = 0; c < 8; ++c) {
            frag8 b_h = *(const frag8*)&Bs_hi[16 * c + lr][q * 8];
            frag8 b_l = *(const frag8*)&Bs_lo[16 * c + lr][q * 8];
#pragma unroll
            for (int r = 0; r < 2; ++r) {
                acc[r][c] = __builtin_amdgcn_mfma_f32_16x16x32_bf16(a_h[r], b_h, acc[r][c], 0, 0, 0);
                acc[r][c] = __builtin_amdgcn_mfma_f32_16x16x32_bf16(a_l[r], b_h, acc[r][c], 0, 0, 0);
                acc[r][c] = __builtin_amdgcn_mfma_f32_16x16x32_bf16(a_h[r], b_l, acc[r][c], 0, 0, 0);
            }
        }
        __syncthreads();
    }
#pragma unroll
    for (int r = 0; r < 2; ++r) {
        int mb = m0 + 32 * w + 16 * r + 4 * q;
#pragma unroll
        for (int reg = 0; reg < 4; ++reg) {
            int m = mb + reg;
            float dv = dinv[s * N + m];
            float* yr = y + ((size_t)s * N + m) * D;
#pragma unroll
            for (int c = 0; c < 8; ++c)
                yr[16 * c + lr] = acc[r][c][reg] * dv;
        }
    }
}

// ---------------- layers 1,2: y = dinv .* (z @ W), split-bf16 MFMA ----------------
__global__ __launch_bounds__(128) void k_xw_mfma(
    const float* __restrict__ zin,
    const unsigned short* __restrict__ wth, const unsigned short* __restrict__ wtl,
    const float* __restrict__ dinv, float* __restrict__ y)
{
    __shared__ __align__(16) unsigned short As_hi[64][32], As_lo[64][32];
    __shared__ __align__(16) unsigned short Bs_hi[128][32], Bs_lo[128][32];
    int m0 = blockIdx.x * 64;
    int tid = threadIdx.x;
    int lane = tid & 63, w = tid >> 6;
    int lr = lane & 15, q = lane >> 4;

    floatx4 acc[2][8];
#pragma unroll
    for (int r = 0; r < 2; ++r)
#pragma unroll
        for (int c = 0; c < 8; ++c)
            acc[r][c] = (floatx4){0.f, 0.f, 0.f, 0.f};

    for (int kc = 0; kc < D / 32; ++kc) {
        int k0 = kc * 32;
#pragma unroll
        for (int l = 0; l < 4; ++l) {
            int i2 = tid + l * 128;
            int row = i2 >> 3, q4 = i2 & 7;
            float4 v = *(const float4*)(zin + (size_t)(m0 + row) * D + k0 + q4 * 4);
            ushort4 h, lo;
            split1(v.x, h.x, lo.x); split1(v.y, h.y, lo.y);
            split1(v.z, h.z, lo.z); split1(v.w, h.w, lo.w);
            *(ushort4*)&As_hi[row][q4 * 4] = h;
            *(ushort4*)&As_lo[row][q4 * 4] = lo;
        }
#pragma unroll
        for (int l = 0; l < 4; ++l) {
            int i2 = tid + l * 128;
            int n = i2 >> 2, q8 = i2 & 3;
            *(uint4*)&Bs_hi[n][q8 * 8] = *(const uint4*)(wth + (size_t)n * D + k0 + q8 * 8);
            *(uint4*)&Bs_lo[n][q8 * 8] = *(const uint4*)(wtl + (size_t)n * D + k0 + q8 * 8);
        }
        __syncthreads();
        frag8 a_h[2], a_l[2];
        a_h[0] = *(const frag8*)&As_hi[32 * w + lr][q * 8];
        a_h[1] = *(const frag8*)&As_hi[32 * w + 16 + lr][q * 8];
        a_l[0] = *(const frag8*)&As_lo[32 * w + lr][q * 8];
        a_l[1] = *(const frag8*)&As_lo[32 * w + 16 + lr][q * 8];
#pragma unroll
        for (int c = 0; c < 8; ++c) {
            frag8 b_h = *(const frag8*)&Bs_hi[16 * c + lr][q * 8];
            frag8 b_l = *(const frag8*)&Bs_lo[16 * c + lr][q * 8];
#pragma unroll
            for (int r = 0; r < 2; ++r) {
                acc[r][c] = __builtin_amdgcn_mfma_f32_16x16x32_bf16(a_h[r], b_h, acc[r][c], 0, 0, 0);
                acc[r][c] = __builtin_amdgcn_mfma_f32_16x16x32_bf16(a_l[r], b_h, acc[r][c], 0, 0, 0);
                acc[r][c] = __builtin_amdgcn_mfma_f32_16x16x32_bf16(a_h[r], b_l, acc[r][c], 0, 0, 0);
            }
        }
        __syncthreads();
    }
#pragma unroll
    for (int r = 0; r < 2; ++r) {
        int mb = m0 + 32 * w + 16 * r + 4 * q;
#pragma unroll
        for (int reg = 0; reg < 4; ++reg) {
            int m = mb + reg;
            float dv = dinv[m];
            float* yr = y + (size_t)m * D;
#pragma unroll
            for (int c = 0; c < 8; ++c)
                yr[16 * c + lr] = acc[r][c][reg] * dv;
        }
    }
}

// ---------------- sparse propagate via CSR, 8-deep pipelined ----------------
__global__ __launch_bounds__(256) void k_prop_csr(
    const unsigned short* __restrict__ idx, const int* __restrict__ degs,
    const float* __restrict__ dinv,
    const float* __restrict__ yin, const float* __restrict__ bias,
    float* __restrict__ z, float* __restrict__ pooled)
{
    __shared__ unsigned short sidx[8][MAXDEG];
    __shared__ int sdeg[8];
    int s  = blockIdx.y;
    int g  = threadIdx.x >> 5;
    int j  = blockIdx.x * 8 + g;
    int f4 = threadIdx.x & 31;
    const float* ys = yin + (size_t)s * N * D;

    {
        int tg = threadIdx.x >> 5, pair = threadIdx.x & 31;
        const unsigned int* src = (const unsigned int*)(idx + ((size_t)(s * N + blockIdx.x * 8 + tg)) * MAXDEG);
        ((unsigned int*)&sidx[tg][0])[pair] = src[pair];
        if (threadIdx.x < 8) sdeg[threadIdx.x] = degs[s * N + blockIdx.x * 8 + threadIdx.x];
    }
    __syncthreads();

    float4 acc = *(const float4*)(ys + (size_t)j * D + f4 * 4);
    int d = sdeg[g];
    int b = 0;
    for (; b + 8 <= d; b += 8) {
        float4 v[8];
#pragma unroll
        for (int qq = 0; qq < 8; ++qq) {
            int i = sidx[g][b + qq];
            v[qq] = *(const float4*)(ys + (size_t)i * D + f4 * 4);
        }
#pragma unroll
        for (int qq = 0; qq < 8; ++qq) {
            acc.x += v[qq].x; acc.y += v[qq].y; acc.z += v[qq].z; acc.w += v[qq].w;
        }
    }
    for (; b < d; ++b) {
        int i = sidx[g][b];
        float4 v = *(const float4*)(ys + (size_t)i * D + f4 * 4);
        acc.x += v.x; acc.y += v.y; acc.z += v.z; acc.w += v.w;
    }

    float dv = dinv[s * N + j];
    int f = f4 * 4;
    float4 r = { acc.x * dv + bias[f],     acc.y * dv + bias[f + 1],
                 acc.z * dv + bias[f + 2], acc.w * dv + bias[f + 3] };

    if (pooled == nullptr) {
        *(float4*)(z + ((size_t)s * N + j) * D + f) = r;
    } else {
        __shared__ float red[8][D];
        *(float4*)&red[g][f] = r;
        __syncthreads();
        if (threadIdx.x < D) {
            float t = 0.f;
#pragma unroll
            for (int qq = 0; qq < 8; ++qq) t += red[qq][threadIdx.x];
            atomicAdd(pooled + s * D + threadIdx.x, t);
        }
    }
}

// ---------------- softplus + MLP head ----------------
__global__ __launch_bounds__(256) void k_head(
    const float* __restrict__ pooled,
    const float* __restrict__ Wh, const float* __restrict__ bh,
    const float* __restrict__ Wi, const float* __restrict__ bi,
    const float* __restrict__ We, const float* __restrict__ be,
    const float* __restrict__ Wlb, const float* __restrict__ blb,
    const float* __restrict__ Wub, const float* __restrict__ bub,
    float* __restrict__ out)
{
    int s = blockIdx.x;
    int t = threadIdx.x;
    __shared__ float sp[D];
    __shared__ float h[HID];
    if (t < D) {
        float x = pooled[s * D + t];
        sp[t] = (x > 20.f) ? x : log1pf(expf(x));
    }
    __syncthreads();
    {
        float a = bh[t];
        for (int g = 0; g < D; ++g)
            a += sp[g] * Wh[g * HID + t];
        h[t] = a;
    }
    __syncthreads();
    if (t < 100) {
        float a = bi[t];
        for (int k = 0; k < HID; ++k)
            a += h[k] * Wi[k * 100 + t];
        out[s * 100 + t] = a;
    } else if (t < 103) {
        const float* Wv = (t == 100) ? We : (t == 101) ? Wlb : Wub;
        float bv = (t == 100) ? be[0] : (t == 101) ? blb[0] : bub[0];
        float a = bv;
        for (int k = 0; k < HID; ++k)
            a += h[k] * Wv[k];
        out[S * 100 + (t - 100) * S + s] = a;
    }
}

extern "C" void kernel_launch(void* const* d_in, const int* in_sizes, int n_in,
                              void* d_out, int out_size, void* d_ws, size_t ws_size,
                              hipStream_t stream) {
    const float* nf   = (const float*)d_in[0];
    const float* bfm  = (const float*)d_in[1];
    const int*   conn = (const int*)d_in[2];
    const float* W0 = (const float*)d_in[4];
    const float* b0 = (const float*)d_in[5];
    const float* W1 = (const float*)d_in[6];
    const float* b1 = (const float*)d_in[7];
    const float* W2 = (const float*)d_in[8];
    const float* b2 = (const float*)d_in[9];
    const float* Wh = (const float*)d_in[10];
    const float* bh = (const float*)d_in[11];
    const float* Wi = (const float*)d_in[12];
    const float* bi = (const float*)d_in[13];
    const float* We = (const float*)d_in[14];
    const float* be = (const float*)d_in[15];
    const float* Wlb = (const float*)d_in[16];
    const float* blb = (const float*)d_in[17];
    const float* Wub = (const float*)d_in[18];
    const float* bub = (const float*)d_in[19];
    float* out = (float*)d_out;

    char* ws = (char*)d_ws;
    float* ybuf = (float*)ws;                                   // 32 MB
    float* zbuf = (float*)(ws + (1u << 25));                    // 32 MB
    char* base2 = ws + (1u << 26);
    float* dinv = (float*)(base2);                              // 256 KB
    int*   degs = (int*)(base2 + 0x40000);                      // 256 KB
    float* pooled = (float*)(base2 + 0x80000);                  // 64 KB
    unsigned short* idx = (unsigned short*)(base2 + 0x90000);   // 8 MB
    unsigned short* w0th = (unsigned short*)(base2 + 0x890000); // 152 KB (pad 256K)
    unsigned short* w0tl = (unsigned short*)(base2 + 0x8D0000);
    unsigned short* w1th = (unsigned short*)(base2 + 0x910000); // 32 KB (pad 64K)
    unsigned short* w1tl = (unsigned short*)(base2 + 0x920000);
    unsigned short* w2th = (unsigned short*)(base2 + 0x930000);
    unsigned short* w2tl = (unsigned short*)(base2 + 0x940000);

    k_pre<<<S * N / 4, 256, 0, stream>>>(conn, idx, degs, dinv, pooled);
    k_wt<<<(KPAD0 * 128 + 255) / 256, 256, 0, stream>>>(W0, DIN, KPAD0, w0th, w0tl);
    k_wt<<<(D * 128 + 255) / 256, 256, 0, stream>>>(W1, D, D, w1th, w1tl);
    k_wt<<<(D * 128 + 255) / 256, 256, 0, stream>>>(W2, D, D, w2th, w2tl);

    k_y0_mfma<<<dim3(N / 64, S), 128, 0, stream>>>(nf, bfm, w0th, w0tl, dinv, ybuf);
    k_prop_csr<<<dim3(N / 8, S), 256, 0, stream>>>(idx, degs, dinv, ybuf, b0, zbuf, nullptr);
    k_xw_mfma<<<S * N / 64, 128, 0, stream>>>(zbuf, w1th, w1tl, dinv, ybuf);
    k_prop_csr<<<dim3(N / 8, S), 256, 0, stream>>>(idx, degs, dinv, ybuf, b1, zbuf, nullptr);
    k_xw_mfma<<<S * N / 64, 128, 0, stream>>>(zbuf, w2th, w2tl, dinv, ybuf);
    k_prop_csr<<<dim3(N / 8, S), 256, 0, stream>>>(idx, degs, dinv, ybuf, b2, zbuf, pooled);
    k_head<<<S, 256, 0, stream>>>(pooled, Wh, bh, Wi, bi, We, be, Wlb, blb, Wub, bub, out);
}